// Round 18
// baseline (233.482 us; speedup 1.0000x reference)
//
#include <hip/hip_runtime.h>
#include <hip/hip_bf16.h>

#define S_TOT 2274
#define T_TXT 226
#define NIMG  2048
#define DM    1920
#define NH    30
#define HD    64
#define SP    2304   // padded S: 18*128 = 36*64

typedef __attribute__((ext_vector_type(8))) short bf16x8;
typedef __attribute__((ext_vector_type(4))) float f32x4;

__device__ __forceinline__ float bs2f(short u) {
  union { float f; unsigned i; } x; x.i = ((unsigned)(unsigned short)u) << 16; return x.f;
}
__device__ __forceinline__ short f2bs(float f) {
  union { __hip_bfloat16 h; short s; } u; u.h = __float2bfloat16(f); return u.s;
}
__device__ __forceinline__ __hip_bfloat16 f2b(float f) { return __float2bfloat16(f); }

__device__ __forceinline__ void gl2lds16(const void* g, void* l) {
  __builtin_amdgcn_global_load_lds((const __attribute__((address_space(1))) void*)g,
                                   (__attribute__((address_space(3))) void*)l, 16, 0, 0);
}

// hardware 2^x (score domain bounded [-11.6, 11.6]; -1e30 mask underflows to 0)
__device__ __forceinline__ float exp2_hw(float x) {
  float r;
  asm("v_exp_f32 %0, %1" : "=v"(r) : "v"(x));
  return r;
}

// m204 bijective XCD-chunked remap: orig -> logical, nwg = 8*q + r
__device__ __forceinline__ int xcd_remap(int orig, int q, int r) {
  const int xcd = orig & 7, pos = orig >> 3;
  return (xcd < r ? xcd * (q + 1) : r * (q + 1) + (xcd - r) * q) + pos;
}

// ---------------------------------------------------------------------------
// Kernel 0: f32 -> bf16 convert/pack.  (unchanged)
// ---------------------------------------------------------------------------
__global__ __launch_bounds__(256) void k_cvt(
    const float* __restrict__ hs, const float* __restrict__ enc,
    const float* __restrict__ Wq, const float* __restrict__ Wk,
    const float* __restrict__ Wv, const float* __restrict__ Wo,
    __hip_bfloat16* __restrict__ xb, __hip_bfloat16* __restrict__ Wb)
{
  const int which = blockIdx.y;
  const size_t i0 = ((size_t)blockIdx.x * 256 + threadIdx.x) * 8;
  float v[8];
  if (which == 0) {
    if (i0 >= (size_t)SP * DM) return;
    const int s = (int)(i0 / DM);
    const int c = (int)(i0 - (size_t)s * DM);
    if (s < T_TXT) {
      const float* p = enc + (size_t)s * DM + c;
#pragma unroll
      for (int e = 0; e < 8; ++e) v[e] = p[e];
    } else if (s < S_TOT) {
      const float* p = hs + (size_t)(s - T_TXT) * DM + c;
#pragma unroll
      for (int e = 0; e < 8; ++e) v[e] = p[e];
    } else {
#pragma unroll
      for (int e = 0; e < 8; ++e) v[e] = 0.0f;
    }
    bf16x8 o;
#pragma unroll
    for (int e = 0; e < 8; ++e) o[e] = f2bs(v[e]);
    *(bf16x8*)(xb + i0) = o;
  } else {
    if (i0 >= (size_t)DM * DM) return;
    const float* src = (which == 1) ? Wq : (which == 2) ? Wk : (which == 3) ? Wv : Wo;
#pragma unroll
    for (int e = 0; e < 8; ++e) v[e] = src[i0 + e];
    bf16x8 o;
#pragma unroll
    for (int e = 0; e < 8; ++e) o[e] = f2bs(v[e]);
    *(bf16x8*)(Wb + (size_t)(which - 1) * DM * DM + i0) = o;
  }
}

// ---------------------------------------------------------------------------
// Kernel 1: fused QKV GEMM + bias + per-head LayerNorm + RoPE.
// r16-verified: BK=64 + __launch_bounds__(256,4).  (unchanged)
// ---------------------------------------------------------------------------
__global__ __launch_bounds__(256, 4) void k_qkv(
    const __hip_bfloat16* __restrict__ xb, const __hip_bfloat16* __restrict__ Wb,
    const float* __restrict__ cosb, const float* __restrict__ sinb,
    const float* __restrict__ bq, const float* __restrict__ bk,
    const float* __restrict__ bv,
    const float* __restrict__ nqw, const float* __restrict__ nqb,
    const float* __restrict__ nkw, const float* __restrict__ nkb,
    __hip_bfloat16* __restrict__ Qb, __hip_bfloat16* __restrict__ Kb,
    __hip_bfloat16* __restrict__ Vtb)
{
  __shared__ __align__(16) short As[128 * 64];
  __shared__ __align__(16) short Bs[128 * 64];
  const int t = threadIdx.x, l = t & 63, w = t >> 6;

  const int L = xcd_remap(blockIdx.x, 101, 2);   // 810 = 8*101 + 2
  const int bm = L % 18;
  const int yy = L / 18;
  const int mode = yy / 15;
  const int bn = yy % 15;
  const __hip_bfloat16* W = Wb + (size_t)mode * DM * DM;
  const float* bias = (mode == 0) ? bq : ((mode == 1) ? bk : bv);

  const int rt = t >> 3;                 // staging row within 32-row slab
  const int lc = (t & 7) ^ (rt & 7);     // inverse-swizzled logical chunk
  const __hip_bfloat16* aptr[4];
  const __hip_bfloat16* bptr[4];
#pragma unroll
  for (int i = 0; i < 4; ++i) {
    aptr[i] = xb + (size_t)(bm * 128 + i * 32 + rt) * DM + lc * 8;
    bptr[i] = W + (size_t)(bn * 128 + i * 32 + rt) * DM + lc * 8;
  }

  f32x4 acc[4][4];
#pragma unroll
  for (int m = 0; m < 4; ++m)
#pragma unroll
    for (int n = 0; n < 4; ++n) acc[m][n] = (f32x4){0.f, 0.f, 0.f, 0.f};

  char* AsB = (char*)As;
  char* BsB = (char*)Bs;
  const int g = l >> 4, cl = l & 15;
  const int chx = l & 7;

  for (int k0 = 0; k0 < DM; k0 += 64) {
    __syncthreads();
#pragma unroll
    for (int i = 0; i < 4; ++i) {
      gl2lds16(aptr[i], AsB + i * 4096 + w * 1024);
      gl2lds16(bptr[i], BsB + i * 4096 + w * 1024);
      aptr[i] += 64; bptr[i] += 64;
    }
    asm volatile("s_waitcnt vmcnt(0)" ::: "memory");
    __syncthreads();

    const char* Abase = AsB + ((w >> 1) * 64 + cl) * 128;
    const char* Bbase = BsB + ((w & 1) * 64 + cl) * 128;
#pragma unroll
    for (int ks = 0; ks < 2; ++ks) {
      const int choff = ((ks * 4 + g) ^ chx) * 16;
      bf16x8 af[4], bfr[4];
#pragma unroll
      for (int m = 0; m < 4; ++m) af[m]  = *(const bf16x8*)(Abase + m * 2048 + choff);
#pragma unroll
      for (int n = 0; n < 4; ++n) bfr[n] = *(const bf16x8*)(Bbase + n * 2048 + choff);
#pragma unroll
      for (int m = 0; m < 4; ++m)
#pragma unroll
        for (int n = 0; n < 4; ++n)
          acc[m][n] = __builtin_amdgcn_mfma_f32_16x16x32_bf16(af[m], bfr[n], acc[m][n], 0, 0, 0);
    }
  }

  const int n0 = bn * 128 + (w & 1) * 64;   // wave's output-col base (one head)
  const int h = n0 >> 6;
  const int srow0 = bm * 128 + (w >> 1) * 64;

  if (mode < 2) {
    const float* nw = (mode == 0) ? nqw : nkw;
    const float* nb = (mode == 0) ? nqb : nkb;
    float wv[4], bvv[4], bf_[4];
#pragma unroll
    for (int n = 0; n < 4; ++n) {
      int c = n * 16 + cl;
      wv[n] = nw[c]; bvv[n] = nb[c]; bf_[n] = bias[n0 + c];
    }
    __hip_bfloat16* dst = ((mode == 0) ? Qb : Kb) + (size_t)h * SP * HD;
#pragma unroll
    for (int m = 0; m < 4; ++m) {
#pragma unroll
      for (int j = 0; j < 4; ++j) {
        int s = srow0 + m * 16 + g * 4 + j;   // D row = (lane>>4)*4 + reg  [m91]
        float v[4];
#pragma unroll
        for (int n = 0; n < 4; ++n) v[n] = acc[m][n][j] + bf_[n];
        float s1 = v[0] + v[1] + v[2] + v[3];
        float s2 = v[0]*v[0] + v[1]*v[1] + v[2]*v[2] + v[3]*v[3];
#pragma unroll
        for (int off = 1; off < 16; off <<= 1) {
          s1 += __shfl_xor(s1, off);
          s2 += __shfl_xor(s2, off);
        }
        float mean = s1 * (1.0f / 64.0f);
        float var  = s2 * (1.0f / 64.0f) - mean * mean;
        float rstd = rsqrtf(var + 1e-5f);
        int pos = s - T_TXT; pos = pos < 0 ? 0 : (pos >= NIMG ? NIMG - 1 : pos);
        bool img = (s >= T_TXT);
#pragma unroll
        for (int n = 0; n < 4; ++n) {
          float y = (v[n] - mean) * rstd * wv[n] + bvv[n];
          float cs = cosb[pos * HD + n * 16 + cl];
          float sn = sinb[pos * HD + n * 16 + cl];
          float part = __shfl_xor(y, 1);      // RoPE pair partner (col c^1, same row)
          float rop = (cl & 1) ? fmaf(part, sn, y * cs) : fmaf(-part, sn, y * cs);
          y = img ? rop : y;
          v[n] = (s < S_TOT) ? y : 0.0f;      // zero-fill pad rows
        }
#pragma unroll
        for (int n = 0; n < 4; ++n)
          dst[(size_t)s * HD + n * 16 + cl] = f2b(v[n]);
      }
    }
  } else {
    float bf_[4];
#pragma unroll
    for (int n = 0; n < 4; ++n) bf_[n] = bias[n0 + n * 16 + cl];
    __hip_bfloat16* dst = Vtb + (size_t)h * HD * SP;
#pragma unroll
    for (int m = 0; m < 4; ++m) {
#pragma unroll
      for (int j = 0; j < 4; ++j) {
        int s = srow0 + m * 16 + g * 4 + j;
#pragma unroll
        for (int n = 0; n < 4; ++n) {
          float y = acc[m][n][j] + bf_[n];
          y = (s < S_TOT) ? y : 0.0f;         // zero pad cols
          dst[(size_t)(n * 16 + cl) * SP + s] = f2b(y);
        }
      }
    }
  }
}

// ---------------------------------------------------------------------------
// Kernel 2: flash attention, max-free, 32 q-rows/wave (r14-verified body)
// + HW exp2 (r15-verified). LDS-BW analysis (r17): K/V fragment reads are
// replicated per wave, so amortize over 2x q-rows: 432 LDS-cy/32 rows vs
// 624/32 in the 16-row variant -> ~30% less LDS pipe time.
// 4 waves, grid 540 = 8*67+4, LDS 40 KB (4 blocks/CU), vmcnt(4).
// ---------------------------------------------------------------------------
__global__ __launch_bounds__(256) void k_attn(
    const __hip_bfloat16* __restrict__ Qb, const __hip_bfloat16* __restrict__ Kb,
    const __hip_bfloat16* __restrict__ Vtb, __hip_bfloat16* __restrict__ Ob)
{
  __shared__ __align__(16) short Ks[2][64 * 64];   // 16 KB
  __shared__ __align__(16) short Vs[2][64 * 64];   // 16 KB
  __shared__ __align__(16) short Pl[4][16 * 64];   // 8 KB (per-wave 2 KB, reused per m)
  const int t = threadIdx.x, l = t & 63, w = t >> 6;
  const int g = l >> 4, cl = l & 15;
  const int cb = cl & 7;

  // bijective XCD remap (m204): 540 = 8*67 + 4
  const int L = xcd_remap(blockIdx.x, 67, 4);
  const int h = L / 18;
  const int bm = L % 18;
  const int q0 = bm * 128 + w * 32;

  const __hip_bfloat16* Qh = Qb + (size_t)h * SP * HD;
  const __hip_bfloat16* Kh = Kb + (size_t)h * SP * HD;
  const __hip_bfloat16* Vh = Vtb + (size_t)h * HD * SP;
  char* myP = (char*)&Pl[w][0];
  char* KsB = (char*)Ks;
  char* VsB = (char*)Vs;

  const int srow = l >> 3;
  const int slot = l & 7;

  // prologue: stage tile 0 (pre-swizzled global source, linear LDS)
#pragma unroll
  for (int i = 0; i < 2; ++i) {
    const int seg = w * 2 + i;
    const int row = seg * 8 + srow;
    const int ch = slot ^ (row & 7);
    gl2lds16(Kh + (size_t)row * HD + ch * 8, KsB + seg * 1024);
    gl2lds16(Vh + (size_t)row * SP + 0 + ch * 8, VsB + seg * 1024);
  }

  // Q fragments, pre-scaled by 0.125*log2(e)  (exp2 domain)
  const float QS = 0.125f * 1.4426950408889634f;
  bf16x8 qf[2][2];
#pragma unroll
  for (int m = 0; m < 2; ++m)
#pragma unroll
    for (int ks = 0; ks < 2; ++ks) {
      int qr = q0 + m * 16 + cl;
      bf16x8 raw = *(const bf16x8*)(Qh + (size_t)qr * HD + ks * 32 + g * 8);
      bf16x8 s8;
#pragma unroll
      for (int e = 0; e < 8; ++e) s8[e] = f2bs(bs2f(raw[e]) * QS);
      qf[m][ks] = s8;
    }

  const bf16x8 ones8 = {0x3F80, 0x3F80, 0x3F80, 0x3F80, 0x3F80, 0x3F80, 0x3F80, 0x3F80};

  f32x4 o[2][4], smv[2];
#pragma unroll
  for (int m = 0; m < 2; ++m) {
    smv[m] = (f32x4){0.f, 0.f, 0.f, 0.f};
#pragma unroll
    for (int n = 0; n < 4; ++n) o[m][n] = (f32x4){0.f, 0.f, 0.f, 0.f};
  }

  const int NT = SP / 64;   // 36
  for (int tt = 0; tt < NT; ++tt) {
    const int kv = tt * 64;
    const int cur = tt & 1;

    if (tt + 1 < NT) {
      const int kvn = kv + 64;
#pragma unroll
      for (int i = 0; i < 2; ++i) {
        const int seg = w * 2 + i;
        const int row = seg * 8 + srow;
        const int ch = slot ^ (row & 7);
        gl2lds16(Kh + (size_t)(kvn + row) * HD + ch * 8, KsB + (cur ^ 1) * 8192 + seg * 1024);
        gl2lds16(Vh + (size_t)row * SP + kvn + ch * 8, VsB + (cur ^ 1) * 8192 + seg * 1024);
      }
      asm volatile("s_waitcnt vmcnt(4)" ::: "memory");  // tile tt landed; next in flight
    } else {
      asm volatile("s_waitcnt vmcnt(0)" ::: "memory");
    }
    __syncthreads();

    const char* Kbuf = KsB + cur * 8192;
    const char* Vbuf = VsB + cur * 8192;

    // QK^T from LDS (swizzled read)
    f32x4 sc[2][4];
    __builtin_amdgcn_s_setprio(1);
#pragma unroll
    for (int n = 0; n < 4; ++n) {
      bf16x8 kf0 = *(const bf16x8*)(Kbuf + (n * 16 + cl) * 128 + (((0 + g) ^ cb) << 4));
      bf16x8 kf1 = *(const bf16x8*)(Kbuf + (n * 16 + cl) * 128 + (((4 + g) ^ cb) << 4));
#pragma unroll
      for (int m = 0; m < 2; ++m) {
        f32x4 a = (f32x4){0.f, 0.f, 0.f, 0.f};
        a = __builtin_amdgcn_mfma_f32_16x16x32_bf16(qf[m][0], kf0, a, 0, 0, 0);
        a = __builtin_amdgcn_mfma_f32_16x16x32_bf16(qf[m][1], kf1, a, 0, 0, 0);
        sc[m][n] = a;
      }
    }
    __builtin_amdgcn_s_setprio(0);

    // V fragments (same swizzled offsets; loaded once, reused across m)
    bf16x8 vf[4][2];
#pragma unroll
    for (int n = 0; n < 4; ++n) {
      vf[n][0] = *(const bf16x8*)(Vbuf + (n * 16 + cl) * 128 + (((0 + g) ^ cb) << 4));
      vf[n][1] = *(const bf16x8*)(Vbuf + (n * 16 + cl) * 128 + (((4 + g) ^ cb) << 4));
    }

    // mask invalid kv columns — only the final tile contains any (uniform branch)
    if (tt == NT - 1) {
#pragma unroll
      for (int n = 0; n < 4; ++n) {
        if (kv + n * 16 + cl >= S_TOT) {
#pragma unroll
          for (int m = 0; m < 2; ++m)
#pragma unroll
            for (int r = 0; r < 4; ++r) sc[m][n][r] = -1e30f;
        }
      }
    }

    // p = exp2(sc) directly (LN-bounded scores; HW v_exp_f32)
#pragma unroll
    for (int m = 0; m < 2; ++m) {
#pragma unroll
      for (int n = 0; n < 4; ++n)
#pragma unroll
        for (int r = 0; r < 4; ++r) {
          float p = exp2_hw(sc[m][n][r]);
          int row = g * 4 + r;
          int chunk = ((n * 16 + cl) >> 3) ^ (row & 7);
          *(short*)(myP + row * 128 + chunk * 16 + 2 * (cl & 7)) = f2bs(p);
        }
      // A-fragments of P (swizzled read) -> PV + ones-sum
      bf16x8 pa[2];
#pragma unroll
      for (int ks = 0; ks < 2; ++ks)
        pa[ks] = *(const bf16x8*)(myP + cl * 128 + (((ks * 4 + g) ^ cb) << 4));
      __builtin_amdgcn_s_setprio(1);
#pragma unroll
      for (int n = 0; n < 4; ++n) {
        o[m][n] = __builtin_amdgcn_mfma_f32_16x16x32_bf16(pa[0], vf[n][0], o[m][n], 0, 0, 0);
        o[m][n] = __builtin_amdgcn_mfma_f32_16x16x32_bf16(pa[1], vf[n][1], o[m][n], 0, 0, 0);
      }
      smv[m] = __builtin_amdgcn_mfma_f32_16x16x32_bf16(pa[0], ones8, smv[m], 0, 0, 0);
      smv[m] = __builtin_amdgcn_mfma_f32_16x16x32_bf16(pa[1], ones8, smv[m], 0, 0, 0);
      __builtin_amdgcn_s_setprio(0);
    }

    __syncthreads();   // protect buf[cur] before overwrite at tt+1
  }

#pragma unroll
  for (int m = 0; m < 2; ++m)
#pragma unroll
    for (int r = 0; r < 4; ++r) {
      float inv = 1.0f / smv[m][r];
      int s = q0 + m * 16 + g * 4 + r;
#pragma unroll
      for (int n = 0; n < 4; ++n) {
        float y = (s < S_TOT) ? o[m][n][r] * inv : 0.0f;   // pad rows -> zeros
        Ob[(size_t)s * DM + h * HD + n * 16 + cl] = f2b(y);
      }
    }
}

// ---------------------------------------------------------------------------
// Kernel 3: output projection GEMM + bias -> scatter (f32 out).
// 64x128 tiles, grid 540 (verified round 17).  (unchanged)
// ---------------------------------------------------------------------------
__global__ __launch_bounds__(256, 4) void k_out(
    const __hip_bfloat16* __restrict__ Ob, const __hip_bfloat16* __restrict__ Wo,
    const float* __restrict__ bo, float* __restrict__ out)
{
  __shared__ __align__(16) short As[64 * 64];    // 8 KB
  __shared__ __align__(16) short Bs[128 * 64];   // 16 KB
  const int t = threadIdx.x, l = t & 63, w = t >> 6;

  const int L = xcd_remap(blockIdx.x, 67, 4);   // 540 = 8*67 + 4
  const int bm = L % 36;                        // M tiles of 64 (36 total)
  const int bn = L / 36;                        // N tiles of 128 (15 total)

  const int rt = t >> 3;
  const int lc = (t & 7) ^ (rt & 7);
  const __hip_bfloat16* aptr[2];
  const __hip_bfloat16* bptr[4];
#pragma unroll
  for (int i = 0; i < 2; ++i)
    aptr[i] = Ob + (size_t)(bm * 64 + i * 32 + rt) * DM + lc * 8;
#pragma unroll
  for (int i = 0; i < 4; ++i)
    bptr[i] = Wo + (size_t)(bn * 128 + i * 32 + rt) * DM + lc * 8;

  f32x4 acc[2][4];
#pragma unroll
  for (int m = 0; m < 2; ++m)
#pragma unroll
    for (int n = 0; n < 4; ++n) acc[m][n] = (f32x4){0.f, 0.f, 0.f, 0.f};

  char* AsB = (char*)As;
  char* BsB = (char*)Bs;
  const int g = l >> 4, cl = l & 15;
  const int chx = l & 7;

  for (int k0 = 0; k0 < DM; k0 += 64) {
    __syncthreads();
#pragma unroll
    for (int i = 0; i < 2; ++i) {
      gl2lds16(aptr[i], AsB + i * 4096 + w * 1024);
      aptr[i] += 64;
    }
#pragma unroll
    for (int i = 0; i < 4; ++i) {
      gl2lds16(bptr[i], BsB + i * 4096 + w * 1024);
      bptr[i] += 64;
    }
    asm volatile("s_waitcnt vmcnt(0)" ::: "memory");
    __syncthreads();

    const char* Abase = AsB + ((w >> 1) * 32 + cl) * 128;
    const char* Bbase = BsB + ((w & 1) * 64 + cl) * 128;
#pragma unroll
    for (int ks = 0; ks < 2; ++ks) {
      const int choff = ((ks * 4 + g) ^ chx) * 16;
      bf16x8 af[2], bfr[4];
#pragma unroll
      for (int m = 0; m < 2; ++m) af[m]  = *(const bf16x8*)(Abase + m * 2048 + choff);
#pragma unroll
      for (int n = 0; n < 4; ++n) bfr[n] = *(const bf16x8*)(Bbase + n * 2048 + choff);
#pragma unroll
      for (int m = 0; m < 2; ++m)
#pragma unroll
        for (int n = 0; n < 4; ++n)
          acc[m][n] = __builtin_amdgcn_mfma_f32_16x16x32_bf16(af[m], bfr[n], acc[m][n], 0, 0, 0);
    }
  }

  const int n0 = bn * 128 + (w & 1) * 64;
  const int srow0 = bm * 64 + (w >> 1) * 32;
  float bf_[4];
#pragma unroll
  for (int n = 0; n < 4; ++n) bf_[n] = bo[n0 + n * 16 + cl];

#pragma unroll
  for (int m = 0; m < 2; ++m) {
#pragma unroll
    for (int j = 0; j < 4; ++j) {
      int s = srow0 + m * 16 + g * 4 + j;
      if (s < S_TOT) {
        size_t rowoff = (s >= T_TXT) ? (size_t)(s - T_TXT) * DM            // hidden first
                                     : (size_t)NIMG * DM + (size_t)s * DM; // then encoder
#pragma unroll
        for (int n = 0; n < 4; ++n)
          out[rowoff + n0 + n * 16 + cl] = acc[m][n][j] + bf_[n];
      }
    }
  }
}

extern "C" void kernel_launch(void* const* d_in, const int* in_sizes, int n_in,
                              void* d_out, int out_size, void* d_ws, size_t ws_size,
                              hipStream_t stream) {
  const float* hs   = (const float*)d_in[0];
  const float* enc  = (const float*)d_in[1];
  const float* cosb = (const float*)d_in[2];
  const float* sinb = (const float*)d_in[3];
  const float* Wq   = (const float*)d_in[4];
  const float* bq   = (const float*)d_in[5];
  const float* Wk   = (const float*)d_in[6];
  const float* bk   = (const float*)d_in[7];
  const float* Wv   = (const float*)d_in[8];
  const float* bv   = (const float*)d_in[9];
  const float* nqw  = (const float*)d_in[10];
  const float* nqb  = (const float*)d_in[11];
  const float* nkw  = (const float*)d_in[12];
  const float* nkb  = (const float*)d_in[13];
  const float* Wo   = (const float*)d_in[14];
  const float* bo   = (const float*)d_in[15];
  float* out = (float*)d_out;               // reference output dtype is float32

  const size_t NE = (size_t)NH * SP * HD;       // 4,423,680 elems per buffer
  __hip_bfloat16* Qb  = (__hip_bfloat16*)d_ws;  // 8.85 MB each
  __hip_bfloat16* Kb  = Qb + NE;
  __hip_bfloat16* Vtb = Kb + NE;
  __hip_bfloat16* Ob  = Vtb + NE;               // (SP, 1920) bf16
  __hip_bfloat16* xb  = Ob + NE;                // (SP, 1920) concat+pad bf16
  __hip_bfloat16* Wb  = xb + (size_t)SP * DM;   // Wq,Wk,Wv,Wo bf16 contiguous
  // total d_ws: 4*NE*2 + SP*DM*2 + 4*DM*DM*2 = 73.7 MB (verified fit)

  k_cvt<<<dim3(2160, 5), 256, 0, stream>>>(hs, enc, Wq, Wk, Wv, Wo, xb, Wb);
  k_qkv<<<dim3(810), 256, 0, stream>>>(xb, Wb, cosb, sinb, bq, bk, bv,
                                       nqw, nqb, nkw, nkb, Qb, Kb, Vtb);
  k_attn<<<dim3(540), 256, 0, stream>>>(Qb, Kb, Vtb, Ob);
  k_out<<<dim3(540), 256, 0, stream>>>(Ob, Wb + 3 * (size_t)DM * DM, bo, out);
}

// Round 19
// 206.252 us; speedup vs baseline: 1.1320x; 1.1320x over previous
//
#include <hip/hip_runtime.h>
#include <hip/hip_bf16.h>

#define S_TOT 2274
#define T_TXT 226
#define NIMG  2048
#define DM    1920
#define NH    30
#define HD    64
#define SP    2304   // padded S: 18*128 = 36*64

typedef __attribute__((ext_vector_type(8))) short bf16x8;
typedef __attribute__((ext_vector_type(4))) float f32x4;

__device__ __forceinline__ float bs2f(short u) {
  union { float f; unsigned i; } x; x.i = ((unsigned)(unsigned short)u) << 16; return x.f;
}
__device__ __forceinline__ short f2bs(float f) {
  union { __hip_bfloat16 h; short s; } u; u.h = __float2bfloat16(f); return u.s;
}
__device__ __forceinline__ __hip_bfloat16 f2b(float f) { return __float2bfloat16(f); }

__device__ __forceinline__ void gl2lds16(const void* g, void* l) {
  __builtin_amdgcn_global_load_lds((const __attribute__((address_space(1))) void*)g,
                                   (__attribute__((address_space(3))) void*)l, 16, 0, 0);
}

// hardware 2^x (score domain bounded [-11.6, 11.6]; -1e30 mask underflows to 0)
__device__ __forceinline__ float exp2_hw(float x) {
  float r;
  asm("v_exp_f32 %0, %1" : "=v"(r) : "v"(x));
  return r;
}

// m204 bijective XCD-chunked remap: orig -> logical, nwg = 8*q + r
__device__ __forceinline__ int xcd_remap(int orig, int q, int r) {
  const int xcd = orig & 7, pos = orig >> 3;
  return (xcd < r ? xcd * (q + 1) : r * (q + 1) + (xcd - r) * q) + pos;
}

// ---------------------------------------------------------------------------
// Kernel 0: f32 -> bf16 convert/pack.  (unchanged)
// ---------------------------------------------------------------------------
__global__ __launch_bounds__(256) void k_cvt(
    const float* __restrict__ hs, const float* __restrict__ enc,
    const float* __restrict__ Wq, const float* __restrict__ Wk,
    const float* __restrict__ Wv, const float* __restrict__ Wo,
    __hip_bfloat16* __restrict__ xb, __hip_bfloat16* __restrict__ Wb)
{
  const int which = blockIdx.y;
  const size_t i0 = ((size_t)blockIdx.x * 256 + threadIdx.x) * 8;
  float v[8];
  if (which == 0) {
    if (i0 >= (size_t)SP * DM) return;
    const int s = (int)(i0 / DM);
    const int c = (int)(i0 - (size_t)s * DM);
    if (s < T_TXT) {
      const float* p = enc + (size_t)s * DM + c;
#pragma unroll
      for (int e = 0; e < 8; ++e) v[e] = p[e];
    } else if (s < S_TOT) {
      const float* p = hs + (size_t)(s - T_TXT) * DM + c;
#pragma unroll
      for (int e = 0; e < 8; ++e) v[e] = p[e];
    } else {
#pragma unroll
      for (int e = 0; e < 8; ++e) v[e] = 0.0f;
    }
    bf16x8 o;
#pragma unroll
    for (int e = 0; e < 8; ++e) o[e] = f2bs(v[e]);
    *(bf16x8*)(xb + i0) = o;
  } else {
    if (i0 >= (size_t)DM * DM) return;
    const float* src = (which == 1) ? Wq : (which == 2) ? Wk : (which == 3) ? Wv : Wo;
#pragma unroll
    for (int e = 0; e < 8; ++e) v[e] = src[i0 + e];
    bf16x8 o;
#pragma unroll
    for (int e = 0; e < 8; ++e) o[e] = f2bs(v[e]);
    *(bf16x8*)(Wb + (size_t)(which - 1) * DM * DM + i0) = o;
  }
}

// ---------------------------------------------------------------------------
// Kernel 1: fused QKV GEMM + bias + per-head LayerNorm + RoPE.
// r16-verified: BK=64 + __launch_bounds__(256,4).  (unchanged)
// ---------------------------------------------------------------------------
__global__ __launch_bounds__(256, 4) void k_qkv(
    const __hip_bfloat16* __restrict__ xb, const __hip_bfloat16* __restrict__ Wb,
    const float* __restrict__ cosb, const float* __restrict__ sinb,
    const float* __restrict__ bq, const float* __restrict__ bk,
    const float* __restrict__ bv,
    const float* __restrict__ nqw, const float* __restrict__ nqb,
    const float* __restrict__ nkw, const float* __restrict__ nkb,
    __hip_bfloat16* __restrict__ Qb, __hip_bfloat16* __restrict__ Kb,
    __hip_bfloat16* __restrict__ Vtb)
{
  __shared__ __align__(16) short As[128 * 64];
  __shared__ __align__(16) short Bs[128 * 64];
  const int t = threadIdx.x, l = t & 63, w = t >> 6;

  const int L = xcd_remap(blockIdx.x, 101, 2);   // 810 = 8*101 + 2
  const int bm = L % 18;
  const int yy = L / 18;
  const int mode = yy / 15;
  const int bn = yy % 15;
  const __hip_bfloat16* W = Wb + (size_t)mode * DM * DM;
  const float* bias = (mode == 0) ? bq : ((mode == 1) ? bk : bv);

  const int rt = t >> 3;                 // staging row within 32-row slab
  const int lc = (t & 7) ^ (rt & 7);     // inverse-swizzled logical chunk
  const __hip_bfloat16* aptr[4];
  const __hip_bfloat16* bptr[4];
#pragma unroll
  for (int i = 0; i < 4; ++i) {
    aptr[i] = xb + (size_t)(bm * 128 + i * 32 + rt) * DM + lc * 8;
    bptr[i] = W + (size_t)(bn * 128 + i * 32 + rt) * DM + lc * 8;
  }

  f32x4 acc[4][4];
#pragma unroll
  for (int m = 0; m < 4; ++m)
#pragma unroll
    for (int n = 0; n < 4; ++n) acc[m][n] = (f32x4){0.f, 0.f, 0.f, 0.f};

  char* AsB = (char*)As;
  char* BsB = (char*)Bs;
  const int g = l >> 4, cl = l & 15;
  const int chx = l & 7;

  for (int k0 = 0; k0 < DM; k0 += 64) {
    __syncthreads();
#pragma unroll
    for (int i = 0; i < 4; ++i) {
      gl2lds16(aptr[i], AsB + i * 4096 + w * 1024);
      gl2lds16(bptr[i], BsB + i * 4096 + w * 1024);
      aptr[i] += 64; bptr[i] += 64;
    }
    asm volatile("s_waitcnt vmcnt(0)" ::: "memory");
    __syncthreads();

    const char* Abase = AsB + ((w >> 1) * 64 + cl) * 128;
    const char* Bbase = BsB + ((w & 1) * 64 + cl) * 128;
#pragma unroll
    for (int ks = 0; ks < 2; ++ks) {
      const int choff = ((ks * 4 + g) ^ chx) * 16;
      bf16x8 af[4], bfr[4];
#pragma unroll
      for (int m = 0; m < 4; ++m) af[m]  = *(const bf16x8*)(Abase + m * 2048 + choff);
#pragma unroll
      for (int n = 0; n < 4; ++n) bfr[n] = *(const bf16x8*)(Bbase + n * 2048 + choff);
#pragma unroll
      for (int m = 0; m < 4; ++m)
#pragma unroll
        for (int n = 0; n < 4; ++n)
          acc[m][n] = __builtin_amdgcn_mfma_f32_16x16x32_bf16(af[m], bfr[n], acc[m][n], 0, 0, 0);
    }
  }

  const int n0 = bn * 128 + (w & 1) * 64;   // wave's output-col base (one head)
  const int h = n0 >> 6;
  const int srow0 = bm * 128 + (w >> 1) * 64;

  if (mode < 2) {
    const float* nw = (mode == 0) ? nqw : nkw;
    const float* nb = (mode == 0) ? nqb : nkb;
    float wv[4], bvv[4], bf_[4];
#pragma unroll
    for (int n = 0; n < 4; ++n) {
      int c = n * 16 + cl;
      wv[n] = nw[c]; bvv[n] = nb[c]; bf_[n] = bias[n0 + c];
    }
    __hip_bfloat16* dst = ((mode == 0) ? Qb : Kb) + (size_t)h * SP * HD;
#pragma unroll
    for (int m = 0; m < 4; ++m) {
#pragma unroll
      for (int j = 0; j < 4; ++j) {
        int s = srow0 + m * 16 + g * 4 + j;   // D row = (lane>>4)*4 + reg  [m91]
        float v[4];
#pragma unroll
        for (int n = 0; n < 4; ++n) v[n] = acc[m][n][j] + bf_[n];
        float s1 = v[0] + v[1] + v[2] + v[3];
        float s2 = v[0]*v[0] + v[1]*v[1] + v[2]*v[2] + v[3]*v[3];
#pragma unroll
        for (int off = 1; off < 16; off <<= 1) {
          s1 += __shfl_xor(s1, off);
          s2 += __shfl_xor(s2, off);
        }
        float mean = s1 * (1.0f / 64.0f);
        float var  = s2 * (1.0f / 64.0f) - mean * mean;
        float rstd = rsqrtf(var + 1e-5f);
        int pos = s - T_TXT; pos = pos < 0 ? 0 : (pos >= NIMG ? NIMG - 1 : pos);
        bool img = (s >= T_TXT);
#pragma unroll
        for (int n = 0; n < 4; ++n) {
          float y = (v[n] - mean) * rstd * wv[n] + bvv[n];
          float cs = cosb[pos * HD + n * 16 + cl];
          float sn = sinb[pos * HD + n * 16 + cl];
          float part = __shfl_xor(y, 1);      // RoPE pair partner (col c^1, same row)
          float rop = (cl & 1) ? fmaf(part, sn, y * cs) : fmaf(-part, sn, y * cs);
          y = img ? rop : y;
          v[n] = (s < S_TOT) ? y : 0.0f;      // zero-fill pad rows
        }
#pragma unroll
        for (int n = 0; n < 4; ++n)
          dst[(size_t)s * HD + n * 16 + cl] = f2b(v[n]);
      }
    }
  } else {
    float bf_[4];
#pragma unroll
    for (int n = 0; n < 4; ++n) bf_[n] = bias[n0 + n * 16 + cl];
    __hip_bfloat16* dst = Vtb + (size_t)h * HD * SP;
#pragma unroll
    for (int m = 0; m < 4; ++m) {
#pragma unroll
      for (int j = 0; j < 4; ++j) {
        int s = srow0 + m * 16 + g * 4 + j;
#pragma unroll
        for (int n = 0; n < 4; ++n) {
          float y = acc[m][n][j] + bf_[n];
          y = (s < S_TOT) ? y : 0.0f;         // zero pad cols
          dst[(size_t)(n * 16 + cl) * SP + s] = f2b(y);
        }
      }
    }
  }
}

// ---------------------------------------------------------------------------
// Kernel 2: flash attention — r16-EXACT REVERT (measured 96.5 us).
// Max-free softmax, QBLK=64 (16 q-rows/wave), grid 1080 = 8*135,
// K/V LDS dbuf + counted vmcnt(4), P-swizzle, HW exp2, setprio.
// (r18's 32-row variant regressed to 124.5 us: occupancy 13% starved the
// longer per-wave chain — LDS-amortization theory refuted.)
// ---------------------------------------------------------------------------
__global__ __launch_bounds__(256) void k_attn(
    const __hip_bfloat16* __restrict__ Qb, const __hip_bfloat16* __restrict__ Kb,
    const __hip_bfloat16* __restrict__ Vtb, __hip_bfloat16* __restrict__ Ob)
{
  __shared__ __align__(16) short Ks[2][64 * 64];   // 16 KB
  __shared__ __align__(16) short Vs[2][64 * 64];   // 16 KB
  __shared__ __align__(16) short Pl[4][16 * 64];   // 8 KB (per-wave 2 KB, swizzled)
  const int t = threadIdx.x, l = t & 63, w = t >> 6;
  const int g = l >> 4, cl = l & 15;
  const int cb = cl & 7;

  // bijective XCD remap: 1080 = 8*135 (r = 0)
  const int L = xcd_remap(blockIdx.x, 135, 0);
  const int h = L / 36;
  const int bm = L % 36;
  const int q0 = bm * 64 + w * 16;

  const __hip_bfloat16* Qh = Qb + (size_t)h * SP * HD;
  const __hip_bfloat16* Kh = Kb + (size_t)h * SP * HD;
  const __hip_bfloat16* Vh = Vtb + (size_t)h * HD * SP;
  char* myP = (char*)&Pl[w][0];
  char* KsB = (char*)Ks;
  char* VsB = (char*)Vs;

  const int srow = l >> 3;
  const int slot = l & 7;

  // prologue: stage tile 0 (pre-swizzled global source, linear LDS)
#pragma unroll
  for (int i = 0; i < 2; ++i) {
    const int seg = w * 2 + i;
    const int row = seg * 8 + srow;
    const int ch = slot ^ (row & 7);
    gl2lds16(Kh + (size_t)row * HD + ch * 8, KsB + seg * 1024);
    gl2lds16(Vh + (size_t)row * SP + 0 + ch * 8, VsB + seg * 1024);
  }

  // Q fragments, pre-scaled by 0.125*log2(e)  (exp2 domain)
  const float QS = 0.125f * 1.4426950408889634f;
  bf16x8 qf[2];
#pragma unroll
  for (int ks = 0; ks < 2; ++ks) {
    int qr = q0 + cl;
    bf16x8 raw = *(const bf16x8*)(Qh + (size_t)qr * HD + ks * 32 + g * 8);
    bf16x8 s8;
#pragma unroll
    for (int e = 0; e < 8; ++e) s8[e] = f2bs(bs2f(raw[e]) * QS);
    qf[ks] = s8;
  }

  const bf16x8 ones8 = {0x3F80, 0x3F80, 0x3F80, 0x3F80, 0x3F80, 0x3F80, 0x3F80, 0x3F80};

  f32x4 o[4], smv;
  smv = (f32x4){0.f, 0.f, 0.f, 0.f};
#pragma unroll
  for (int n = 0; n < 4; ++n) o[n] = (f32x4){0.f, 0.f, 0.f, 0.f};

  const int NT = SP / 64;   // 36
  for (int tt = 0; tt < NT; ++tt) {
    const int kv = tt * 64;
    const int cur = tt & 1;

    if (tt + 1 < NT) {
      const int kvn = kv + 64;
#pragma unroll
      for (int i = 0; i < 2; ++i) {
        const int seg = w * 2 + i;
        const int row = seg * 8 + srow;
        const int ch = slot ^ (row & 7);
        gl2lds16(Kh + (size_t)(kvn + row) * HD + ch * 8, KsB + (cur ^ 1) * 8192 + seg * 1024);
        gl2lds16(Vh + (size_t)row * SP + kvn + ch * 8, VsB + (cur ^ 1) * 8192 + seg * 1024);
      }
      asm volatile("s_waitcnt vmcnt(4)" ::: "memory");  // tile tt landed; next in flight
    } else {
      asm volatile("s_waitcnt vmcnt(0)" ::: "memory");
    }
    __syncthreads();

    const char* Kbuf = KsB + cur * 8192;
    const char* Vbuf = VsB + cur * 8192;

    // QK^T from LDS (swizzled read)
    f32x4 sc[4];
    __builtin_amdgcn_s_setprio(1);
#pragma unroll
    for (int n = 0; n < 4; ++n) {
      bf16x8 kf0 = *(const bf16x8*)(Kbuf + (n * 16 + cl) * 128 + (((0 + g) ^ cb) << 4));
      bf16x8 kf1 = *(const bf16x8*)(Kbuf + (n * 16 + cl) * 128 + (((4 + g) ^ cb) << 4));
      f32x4 a = (f32x4){0.f, 0.f, 0.f, 0.f};
      a = __builtin_amdgcn_mfma_f32_16x16x32_bf16(qf[0], kf0, a, 0, 0, 0);
      a = __builtin_amdgcn_mfma_f32_16x16x32_bf16(qf[1], kf1, a, 0, 0, 0);
      sc[n] = a;
    }
    __builtin_amdgcn_s_setprio(0);

    // V fragments (same swizzled offsets)
    bf16x8 vf[4][2];
#pragma unroll
    for (int n = 0; n < 4; ++n) {
      vf[n][0] = *(const bf16x8*)(Vbuf + (n * 16 + cl) * 128 + (((0 + g) ^ cb) << 4));
      vf[n][1] = *(const bf16x8*)(Vbuf + (n * 16 + cl) * 128 + (((4 + g) ^ cb) << 4));
    }

    // mask invalid kv columns — only the final tile contains any (uniform branch)
    if (tt == NT - 1) {
#pragma unroll
      for (int n = 0; n < 4; ++n) {
        if (kv + n * 16 + cl >= S_TOT) {
#pragma unroll
          for (int r = 0; r < 4; ++r) sc[n][r] = -1e30f;
        }
      }
    }

    // p = exp2(sc) directly (LN-bounded scores; HW v_exp_f32)
#pragma unroll
    for (int n = 0; n < 4; ++n)
#pragma unroll
      for (int r = 0; r < 4; ++r) {
        float p = exp2_hw(sc[n][r]);
        int row = g * 4 + r;
        int chunk = ((n * 16 + cl) >> 3) ^ (row & 7);
        *(short*)(myP + row * 128 + chunk * 16 + 2 * (cl & 7)) = f2bs(p);
      }
    // A-fragments of P (swizzled read) -> PV + ones-sum
    bf16x8 pa[2];
#pragma unroll
    for (int ks = 0; ks < 2; ++ks)
      pa[ks] = *(const bf16x8*)(myP + cl * 128 + (((ks * 4 + g) ^ cb) << 4));
    __builtin_amdgcn_s_setprio(1);
#pragma unroll
    for (int n = 0; n < 4; ++n) {
      o[n] = __builtin_amdgcn_mfma_f32_16x16x32_bf16(pa[0], vf[n][0], o[n], 0, 0, 0);
      o[n] = __builtin_amdgcn_mfma_f32_16x16x32_bf16(pa[1], vf[n][1], o[n], 0, 0, 0);
    }
    smv = __builtin_amdgcn_mfma_f32_16x16x32_bf16(pa[0], ones8, smv, 0, 0, 0);
    smv = __builtin_amdgcn_mfma_f32_16x16x32_bf16(pa[1], ones8, smv, 0, 0, 0);
    __builtin_amdgcn_s_setprio(0);

    __syncthreads();   // protect buf[cur] before overwrite at tt+1
  }

#pragma unroll
  for (int r = 0; r < 4; ++r) {
    float inv = 1.0f / smv[r];
    int s = q0 + g * 4 + r;
#pragma unroll
    for (int n = 0; n < 4; ++n) {
      float y = (s < S_TOT) ? o[n][r] * inv : 0.0f;   // pad rows -> zeros
      Ob[(size_t)s * DM + h * HD + n * 16 + cl] = f2b(y);
    }
  }
}

// ---------------------------------------------------------------------------
// Kernel 3: output projection GEMM + bias -> scatter (f32 out).
// 64x128 tiles, grid 540 (verified round 17).  (unchanged)
// ---------------------------------------------------------------------------
__global__ __launch_bounds__(256, 4) void k_out(
    const __hip_bfloat16* __restrict__ Ob, const __hip_bfloat16* __restrict__ Wo,
    const float* __restrict__ bo, float* __restrict__ out)
{
  __shared__ __align__(16) short As[64 * 64];    // 8 KB
  __shared__ __align__(16) short Bs[128 * 64];   // 16 KB
  const int t = threadIdx.x, l = t & 63, w = t >> 6;

  const int L = xcd_remap(blockIdx.x, 67, 4);   // 540 = 8*67 + 4
  const int bm = L % 36;                        // M tiles of 64 (36 total)
  const int bn = L / 36;                        // N tiles of 128 (15 total)

  const int rt = t >> 3;
  const int lc = (t & 7) ^ (rt & 7);
  const __hip_bfloat16* aptr[2];
  const __hip_bfloat16* bptr[4];
#pragma unroll
  for (int i = 0; i < 2; ++i)
    aptr[i] = Ob + (size_t)(bm * 64 + i * 32 + rt) * DM + lc * 8;
#pragma unroll
  for (int i = 0; i < 4; ++i)
    bptr[i] = Wo + (size_t)(bn * 128 + i * 32 + rt) * DM + lc * 8;

  f32x4 acc[2][4];
#pragma unroll
  for (int m = 0; m < 2; ++m)
#pragma unroll
    for (int n = 0; n < 4; ++n) acc[m][n] = (f32x4){0.f, 0.f, 0.f, 0.f};

  char* AsB = (char*)As;
  char* BsB = (char*)Bs;
  const int g = l >> 4, cl = l & 15;
  const int chx = l & 7;

  for (int k0 = 0; k0 < DM; k0 += 64) {
    __syncthreads();
#pragma unroll
    for (int i = 0; i < 2; ++i) {
      gl2lds16(aptr[i], AsB + i * 4096 + w * 1024);
      aptr[i] += 64;
    }
#pragma unroll
    for (int i = 0; i < 4; ++i) {
      gl2lds16(bptr[i], BsB + i * 4096 + w * 1024);
      bptr[i] += 64;
    }
    asm volatile("s_waitcnt vmcnt(0)" ::: "memory");
    __syncthreads();

    const char* Abase = AsB + ((w >> 1) * 32 + cl) * 128;
    const char* Bbase = BsB + ((w & 1) * 64 + cl) * 128;
#pragma unroll
    for (int ks = 0; ks < 2; ++ks) {
      const int choff = ((ks * 4 + g) ^ chx) * 16;
      bf16x8 af[2], bfr[4];
#pragma unroll
      for (int m = 0; m < 2; ++m) af[m]  = *(const bf16x8*)(Abase + m * 2048 + choff);
#pragma unroll
      for (int n = 0; n < 4; ++n) bfr[n] = *(const bf16x8*)(Bbase + n * 2048 + choff);
#pragma unroll
      for (int m = 0; m < 2; ++m)
#pragma unroll
        for (int n = 0; n < 4; ++n)
          acc[m][n] = __builtin_amdgcn_mfma_f32_16x16x32_bf16(af[m], bfr[n], acc[m][n], 0, 0, 0);
    }
  }

  const int n0 = bn * 128 + (w & 1) * 64;
  const int srow0 = bm * 64 + (w >> 1) * 32;
  float bf_[4];
#pragma unroll
  for (int n = 0; n < 4; ++n) bf_[n] = bo[n0 + n * 16 + cl];

#pragma unroll
  for (int m = 0; m < 2; ++m) {
#pragma unroll
    for (int j = 0; j < 4; ++j) {
      int s = srow0 + m * 16 + g * 4 + j;
      if (s < S_TOT) {
        size_t rowoff = (s >= T_TXT) ? (size_t)(s - T_TXT) * DM            // hidden first
                                     : (size_t)NIMG * DM + (size_t)s * DM; // then encoder
#pragma unroll
        for (int n = 0; n < 4; ++n)
          out[rowoff + n0 + n * 16 + cl] = acc[m][n][j] + bf_[n];
      }
    }
  }
}

extern "C" void kernel_launch(void* const* d_in, const int* in_sizes, int n_in,
                              void* d_out, int out_size, void* d_ws, size_t ws_size,
                              hipStream_t stream) {
  const float* hs   = (const float*)d_in[0];
  const float* enc  = (const float*)d_in[1];
  const float* cosb = (const float*)d_in[2];
  const float* sinb = (const float*)d_in[3];
  const float* Wq   = (const float*)d_in[4];
  const float* bq   = (const float*)d_in[5];
  const float* Wk   = (const float*)d_in[6];
  const float* bk   = (const float*)d_in[7];
  const float* Wv   = (const float*)d_in[8];
  const float* bv   = (const float*)d_in[9];
  const float* nqw  = (const float*)d_in[10];
  const float* nqb  = (const float*)d_in[11];
  const float* nkw  = (const float*)d_in[12];
  const float* nkb  = (const float*)d_in[13];
  const float* Wo   = (const float*)d_in[14];
  const float* bo   = (const float*)d_in[15];
  float* out = (float*)d_out;               // reference output dtype is float32

  const size_t NE = (size_t)NH * SP * HD;       // 4,423,680 elems per buffer
  __hip_bfloat16* Qb  = (__hip_bfloat16*)d_ws;  // 8.85 MB each
  __hip_bfloat16* Kb  = Qb + NE;
  __hip_bfloat16* Vtb = Kb + NE;
  __hip_bfloat16* Ob  = Vtb + NE;               // (SP, 1920) bf16
  __hip_bfloat16* xb  = Ob + NE;                // (SP, 1920) concat+pad bf16
  __hip_bfloat16* Wb  = xb + (size_t)SP * DM;   // Wq,Wk,Wv,Wo bf16 contiguous
  // total d_ws: 4*NE*2 + SP*DM*2 + 4*DM*DM*2 = 73.7 MB (verified fit)

  k_cvt<<<dim3(2160, 5), 256, 0, stream>>>(hs, enc, Wq, Wk, Wv, Wo, xb, Wb);
  k_qkv<<<dim3(810), 256, 0, stream>>>(xb, Wb, cosb, sinb, bq, bk, bv,
                                       nqw, nqb, nkw, nkb, Qb, Kb, Vtb);
  k_attn<<<dim3(1080), 256, 0, stream>>>(Qb, Kb, Vtb, Ob);
  k_out<<<dim3(540), 256, 0, stream>>>(Ob, Wb + 3 * (size_t)DM * DM, bo, out);
}